// Round 3
// baseline (204.486 us; speedup 1.0000x reference)
//
#include <hip/hip_runtime.h>

#define S_LEN 2048
#define DMODEL 1024
#define NHEAD 16
#define DHEAD 64
#define BATCH 2
#define BH_TOT (BATCH * NHEAD)   // 32
#define TOK (BATCH * S_LEN)      // 4096
#define NQKV (3 * DMODEL)        // 3072

// softmax scale 1/sqrt(64) = 0.125, fused with log2(e) so scores are in log2 domain
#define QSCALE 0.18033688011112042f

typedef float  f32x4  __attribute__((ext_vector_type(4)));
typedef float  f32x16 __attribute__((ext_vector_type(16)));
typedef int    i32x4  __attribute__((ext_vector_type(4)));
typedef __bf16 bf16x8 __attribute__((ext_vector_type(8)));
typedef __bf16 bf16x4 __attribute__((ext_vector_type(4)));
typedef __bf16 bf16x2 __attribute__((ext_vector_type(2)));

typedef __attribute__((address_space(1))) void* as1_ptr;
typedef __attribute__((address_space(3))) void* as3_ptr;

__device__ __forceinline__ void gl2lds16(const void* g, void* l) {
  __builtin_amdgcn_global_load_lds((as1_ptr)(void*)g, (as3_ptr)l, 16, 0, 0);
}

__device__ __forceinline__ f32x4 mfma32(bf16x8 a, bf16x8 b, f32x4 c) {
  return __builtin_amdgcn_mfma_f32_16x16x32_bf16(a, b, c, 0, 0, 0);
}

// 32x32x16 bf16: A[m=lane&31][k=(lane>>5)*8+j], B[k=(lane>>5)*8+j][n=lane&31]
// C/D: col=lane&31, row=(reg&3)+8*(reg>>2)+4*(lane>>5)
__device__ __forceinline__ f32x16 mfma3216(bf16x8 a, bf16x8 b, f32x16 c) {
  return __builtin_amdgcn_mfma_f32_32x32x16_bf16(a, b, c, 0, 0, 0);
}

// pack 2 f32 -> 1 word of 2 bf16 via scalar casts (compiler emits the pack; per T12/m240
// this beats hand-written v_cvt_pk_bf16_f32 and has no operand-order ambiguity)
__device__ __forceinline__ unsigned pack2(float a, float b) {
  bf16x2 t;
  t[0] = (__bf16)a;
  t[1] = (__bf16)b;
  return __builtin_bit_cast(unsigned, t);
}

// Build the 32x32x16 B-fragment (16 keys x 32 q) from 8 post-exp P values.
// Input: lane (c31,hi) holds p[key=(r&3)+8*(r>>2)+4*hi][q=c31] for r=0..7 of one 16-key chunk.
// Target B-layout: lane (c31,hi) holds B[k=hi*8+j][n=c31], j=0..7.
// Cross-half exchange via __shfl_xor(.,32) + select — correct regardless of the
// permlane32_swap direction convention (which R1 got wrong).
__device__ __forceinline__ bf16x8 pfrag8(int hi,
                                         float a0, float a1, float a2, float a3,
                                         float a4, float a5, float a6, float a7) {
  const unsigned wA = pack2(a0, a1);   // hi=0: {k0,k1}   hi=1: {k4,k5}
  const unsigned wB = pack2(a2, a3);   // hi=0: {k2,k3}   hi=1: {k6,k7}
  const unsigned wC = pack2(a4, a5);   // hi=0: {k8,k9}   hi=1: {k12,k13}
  const unsigned wD = pack2(a6, a7);   // hi=0: {k10,k11} hi=1: {k14,k15}
  const unsigned sA = (unsigned)__shfl_xor((int)wA, 32);
  const unsigned sB = (unsigned)__shfl_xor((int)wB, 32);
  const unsigned sC = (unsigned)__shfl_xor((int)wC, 32);
  const unsigned sD = (unsigned)__shfl_xor((int)wD, 32);
  const unsigned r0 = hi ? sC : wA;    // {k0,k1}   / {k8,k9}
  const unsigned r1 = hi ? sD : wB;    // {k2,k3}   / {k10,k11}
  const unsigned r2 = hi ? wC : sA;    // {k4,k5}   / {k12,k13}
  const unsigned r3 = hi ? wD : sB;    // {k6,k7}   / {k14,k15}
  const i32x4 w = {(int)r0, (int)r1, (int)r2, (int)r3};
  return __builtin_bit_cast(bf16x8, w);
}

// ---------------------------------------------------------------- convert f32 -> bf16
__global__ __launch_bounds__(256) void cvt_kernel(const float* __restrict__ src,
                                                  __bf16* __restrict__ dst, int n) {
  const int i = (blockIdx.x * 256 + threadIdx.x) * 4;
  if (i >= n) return;
  const f32x4 v = *(const f32x4*)(src + i);
  bf16x4 o;
  o[0] = (__bf16)v[0]; o[1] = (__bf16)v[1]; o[2] = (__bf16)v[2]; o[3] = (__bf16)v[3];
  *(bf16x4*)(dst + i) = o;
}

// ---------------------------------------------------------------- 128x128 bf16 GEMM mainloop
__device__ __forceinline__ void gemm_tile_128(const __bf16* __restrict__ A,
                                              const __bf16* __restrict__ Bw,
                                              const int Kd, const int tileM, const int tileN,
                                              __bf16* As, __bf16* Bs, f32x4 acc[4][4]) {
  const int t    = threadIdx.x;
  const int lane = t & 63;
  const int wave = t >> 6;
  const int quad = lane >> 4;
  const int c    = lane & 15;
  const int wm   = (wave >> 1) << 6;
  const int wn   = (wave & 1) << 6;

  const int u0 = t, u1 = t + 256;
  const __bf16* gA0 = A  + (size_t)(tileM + (u0 >> 2)) * Kd + (u0 & 3) * 8;
  const __bf16* gA1 = A  + (size_t)(tileM + (u1 >> 2)) * Kd + (u1 & 3) * 8;
  const __bf16* gB0 = Bw + (size_t)(tileN + (u0 >> 2)) * Kd + (u0 & 3) * 8;
  const __bf16* gB1 = Bw + (size_t)(tileN + (u1 >> 2)) * Kd + (u1 & 3) * 8;
  __bf16* lA0 = As + u0 * 8; __bf16* lA1 = As + u1 * 8;
  __bf16* lB0 = Bs + u0 * 8; __bf16* lB1 = Bs + u1 * 8;

  for (int k0 = 0; k0 < Kd; k0 += 32) {
    gl2lds16(gA0 + k0, lA0);
    gl2lds16(gA1 + k0, lA1);
    gl2lds16(gB0 + k0, lB0);
    gl2lds16(gB1 + k0, lB1);
    __syncthreads();
    bf16x8 af[4], bfr[4];
#pragma unroll
    for (int mt = 0; mt < 4; ++mt)
      af[mt] = *(const bf16x8*)(As + (wm + mt * 16 + c) * 32 + quad * 8);
#pragma unroll
    for (int nt = 0; nt < 4; ++nt)
      bfr[nt] = *(const bf16x8*)(Bs + (wn + nt * 16 + c) * 32 + quad * 8);
#pragma unroll
    for (int mt = 0; mt < 4; ++mt)
#pragma unroll
      for (int nt = 0; nt < 4; ++nt)
        acc[mt][nt] = mfma32(af[mt], bfr[nt], acc[mt][nt]);
    __syncthreads();
  }
}

// ---------------------------------------------------------------- QKV projection (+V transpose fused, +Q log2-scale)
__global__ __launch_bounds__(256) void gemm_qkv_kernel(const __bf16* __restrict__ xb,
                                                       const __bf16* __restrict__ Wb,
                                                       const float* __restrict__ bias,
                                                       __bf16* __restrict__ Qb,
                                                       __bf16* __restrict__ Kb,
                                                       __bf16* __restrict__ Vtb) {
  __shared__ __align__(16) __bf16 As[128 * 32];
  __shared__ __align__(16) __bf16 Bs[128 * 32];
  f32x4 acc[4][4];
#pragma unroll
  for (int i = 0; i < 4; ++i)
#pragma unroll
    for (int j = 0; j < 4; ++j) acc[i][j] = (f32x4){0.f, 0.f, 0.f, 0.f};

  const int tileM = blockIdx.y * 128;
  const int tileN = blockIdx.x * 128;
  gemm_tile_128(xb, Wb, DMODEL, tileM, tileN, As, Bs, acc);

  const int t = threadIdx.x;
  const int lane = t & 63, wave = t >> 6;
  const int quad = lane >> 4, c = lane & 15;
  const int wm = (wave >> 1) << 6, wn = (wave & 1) << 6;

#pragma unroll
  for (int nt = 0; nt < 4; ++nt) {
    const int col = tileN + wn + nt * 16 + c;
    const float bv = bias[col];
    const int which = col >> 10;         // 0=q,1=k,2=v  (uniform within 16-col group)
    const int h  = (col >> 6) & 15;
    const int dh = col & 63;
    if (which == 2) {
#pragma unroll
      for (int mt = 0; mt < 4; ++mt) {
        const int row0 = tileM + wm + mt * 16 + quad * 4;
        const int bb = row0 >> 11;
        const int ss = row0 & (S_LEN - 1);
        bf16x4 o;
#pragma unroll
        for (int r = 0; r < 4; ++r) o[r] = (__bf16)(acc[mt][nt][r] + bv);
        *(bf16x4*)(Vtb + (((size_t)(bb * NHEAD + h)) * DHEAD + dh) * S_LEN + ss) = o;
      }
    } else {
      __bf16* dst = (which == 0) ? Qb : Kb;
      const float scl = (which == 0) ? QSCALE : 1.0f;
#pragma unroll
      for (int mt = 0; mt < 4; ++mt) {
#pragma unroll
        for (int r = 0; r < 4; ++r) {
          const int row = tileM + wm + mt * 16 + quad * 4 + r;
          const int bb = row >> 11;
          const int ss = row & (S_LEN - 1);
          dst[(((size_t)(bb * NHEAD + h)) * S_LEN + ss) * DHEAD + dh] =
              (__bf16)((acc[mt][nt][r] + bv) * scl);
        }
      }
    }
  }
}

// ---------------------------------------------------------------- output projection
__global__ __launch_bounds__(256) void gemm_out_kernel(const __bf16* __restrict__ AOb,
                                                       const __bf16* __restrict__ Wb,
                                                       const float* __restrict__ bout,
                                                       float* __restrict__ out) {
  __shared__ __align__(16) __bf16 As[128 * 32];
  __shared__ __align__(16) __bf16 Bs[128 * 32];
  f32x4 acc[4][4];
#pragma unroll
  for (int i = 0; i < 4; ++i)
#pragma unroll
    for (int j = 0; j < 4; ++j) acc[i][j] = (f32x4){0.f, 0.f, 0.f, 0.f};

  const int tileM = blockIdx.y * 128;
  const int tileN = blockIdx.x * 128;
  gemm_tile_128(AOb, Wb, DMODEL, tileM, tileN, As, Bs, acc);

  const int t = threadIdx.x;
  const int lane = t & 63, wave = t >> 6;
  const int quad = lane >> 4, c = lane & 15;
  const int wm = (wave >> 1) << 6, wn = (wave & 1) << 6;

#pragma unroll
  for (int nt = 0; nt < 4; ++nt) {
    const int col = tileN + wn + nt * 16 + c;
    const float bv = bout[col];
#pragma unroll
    for (int mt = 0; mt < 4; ++mt) {
#pragma unroll
      for (int r = 0; r < 4; ++r) {
        const int row = tileM + wm + mt * 16 + quad * 4 + r;
        out[(size_t)row * DMODEL + col] = acc[mt][nt][r] + bv;
      }
    }
  }
}

// ---------------------------------------------------------------- partial interleaved RoPE
__global__ __launch_bounds__(256) void rope_kernel(__bf16* __restrict__ Qb, __bf16* __restrict__ Kb) {
  const int idx = blockIdx.x * 256 + threadIdx.x;
  const int j  = idx & 15;
  const int s  = (idx >> 4) & (S_LEN - 1);
  const int bh = (idx >> 15) & (BH_TOT - 1);
  __bf16* base = (idx >> 20) ? Kb : Qb;
  bf16x2* p = (bf16x2*)(base + ((size_t)bh * S_LEN + s) * DHEAD) + j;
  bf16x2 v = *p;
  const float x1 = (float)v[0];
  const float x2 = (float)v[1];
  const float LOG2_10000 = 13.287712379549449f;
  const float inv = exp2f(-(float)j * (LOG2_10000 / 16.0f));
  const float ang = (float)s * inv;
  float sn, cs;
  sincosf(ang, &sn, &cs);
  bf16x2 o;
  o[0] = (__bf16)(x1 * cs - x2 * sn);
  o[1] = (__bf16)(x2 * cs + x1 * sn);
  *p = o;
}

// ---------------------------------------------------------------- flash attention R5 (32x32 MFMA, shfl-based P repack)
// block = 4 waves x 32 q = 128 q; grid (16, 32). K/V^T double-buffered in LDS via
// global_load_lds with XOR-swizzled 16B chunks (chunk ^= row&7).
// Per 64-key tile, per wave:
//   S^T = K·Q^T : 8x mfma_f32_32x32x16_bf16  (K A-frags: 8x ds_read_b128 swizzled)
//   p = exp2(z) (no-max), packed in-register to the PV B-layout (pack2 + shfl_xor(32) + select)
//   O^T += V^T·P^T : 8x mfma_f32_32x32x16_bf16 (V^T A-frags: 8x ds_read_b128 swizzled)
// Split accumulators (ota/otb) keep same-acc MFMA dependency distance >= 4.
// l reduced with ONE shfl_xor(32) at the end (lane & lane^32 cover complementary key rows).
__global__ __launch_bounds__(256, 2) void attn_kernel(const __bf16* __restrict__ Qb,
                                                      const __bf16* __restrict__ Kb,
                                                      const __bf16* __restrict__ Vtb,
                                                      __bf16* __restrict__ AOb) {
  __shared__ __align__(16) __bf16 Ks[2][64 * 64];   // [key][d], swizzled
  __shared__ __align__(16) __bf16 Vts[2][64 * 64];  // [d][key], swizzled

  const int qt = blockIdx.x;
  const int bh = blockIdx.y;
  const int b = bh >> 4, h = bh & 15;
  const int t = threadIdx.x, wave = t >> 6, lane = t & 63;
  const int c31 = lane & 31, hi = lane >> 5;
  const int cx = c31 & 7;
  const size_t head = (size_t)bh * S_LEN * DHEAD;
  const int q0w = qt * 128 + wave * 32;   // this wave's first q

  // Q B-frags (resident): qf[s] = Q^T[k=d=s*16+hi*8+j][n=q=q0w+c31]
  bf16x8 qf[4];
#pragma unroll
  for (int s = 0; s < 4; ++s)
    qf[s] = *(const bf16x8*)(Qb + head + (size_t)(q0w + c31) * DHEAD + s * 16 + hi * 8);

  f32x16 zzero;
#pragma unroll
  for (int i = 0; i < 16; ++i) zzero[i] = 0.f;

  // O^T accumulators: [dblock]; lane holds d = dblock*32+(r&3)+8*(r>>2)+4*hi, q = c31.
  // ota <- 16-key chunks 0/2, otb <- chunks 1/3; summed in the epilogue.
  f32x16 ota[2], otb[2];
  ota[0] = zzero; ota[1] = zzero; otb[0] = zzero; otb[1] = zzero;
  float lp = 0.f;

  // staging unit indices (16B units): u -> row=u>>3, chunk=u&7; source chunk XOR row&7
  const int u0 = t, u1 = t + 256;
  const int r0 = u0 >> 3, ch0 = (u0 & 7) ^ (r0 & 7);
  const int r1 = u1 >> 3, ch1 = (u1 & 7) ^ (r1 & 7);
  const __bf16* kg0 = Kb + head + (size_t)r0 * DHEAD + ch0 * 8;
  const __bf16* kg1 = Kb + head + (size_t)r1 * DHEAD + ch1 * 8;
  const __bf16* vg0 = Vtb + ((size_t)bh * DHEAD + r0) * S_LEN + ch0 * 8;
  const __bf16* vg1 = Vtb + ((size_t)bh * DHEAD + r1) * S_LEN + ch1 * 8;

  // stage kb=0 into buffer 0
  gl2lds16(kg0, &Ks[0][u0 * 8]);
  gl2lds16(kg1, &Ks[0][u1 * 8]);
  gl2lds16(vg0, &Vts[0][u0 * 8]);
  gl2lds16(vg1, &Vts[0][u1 * 8]);

#define VREAD(db, gch) \
  (*(const bf16x8*)(&Vts[cur][((db) * 32 + c31) * 64 + ((((gch) + hi) ^ cx) * 8)]))

  for (int kb = 0; kb < S_LEN / 64; ++kb) {
    __syncthreads();   // drains this wave's DMA (vmcnt) + syncs all waves
    const int cur = kb & 1;
    if (kb + 1 < S_LEN / 64) {
      const int nxt = cur ^ 1;
      const int k0n = (kb + 1) * 64;
      gl2lds16(kg0 + (size_t)k0n * DHEAD, &Ks[nxt][u0 * 8]);
      gl2lds16(kg1 + (size_t)k0n * DHEAD, &Ks[nxt][u1 * 8]);
      gl2lds16(vg0 + k0n, &Vts[nxt][u0 * 8]);
      gl2lds16(vg1 + k0n, &Vts[nxt][u1 * 8]);
    }

    // K A-frags: A[m=key=kb2*32+c31][k=d=s*16+hi*8+j], XOR-swizzled b128
    bf16x8 kA0[4], kA1[4];
#pragma unroll
    for (int s = 0; s < 4; ++s) {
      kA0[s] = *(const bf16x8*)(&Ks[cur][c31 * 64 + (((s * 2 + hi) ^ cx) * 8)]);
      kA1[s] = *(const bf16x8*)(&Ks[cur][(32 + c31) * 64 + (((s * 2 + hi) ^ cx) * 8)]);
    }

    // S^T for both 32-key halves (interleaved -> dependent-MFMA distance 2)
    f32x16 z0 = zzero, z1 = zzero;
#pragma unroll
    for (int s = 0; s < 4; ++s) {
      z0 = mfma3216(kA0[s], qf[s], z0);
      z1 = mfma3216(kA1[s], qf[s], z1);
    }

    float p0[16], p1[16];
#pragma unroll
    for (int r = 0; r < 16; ++r) p0[r] = __builtin_amdgcn_exp2f(z0[r]);
#pragma unroll
    for (int r = 0; r < 16; ++r) p1[r] = __builtin_amdgcn_exp2f(z1[r]);

    lp += (((p0[0] + p0[1]) + (p0[2] + p0[3])) + ((p0[4] + p0[5]) + (p0[6] + p0[7])))
        + (((p0[8] + p0[9]) + (p0[10] + p0[11])) + ((p0[12] + p0[13]) + (p0[14] + p0[15])));
    lp += (((p1[0] + p1[1]) + (p1[2] + p1[3])) + ((p1[4] + p1[5]) + (p1[6] + p1[7])))
        + (((p1[8] + p1[9]) + (p1[10] + p1[11])) + ((p1[12] + p1[13]) + (p1[14] + p1[15])));

    // PV, keys kb*64 + 0..31
    {
      const bf16x8 f0 = pfrag8(hi, p0[0], p0[1], p0[2], p0[3], p0[4], p0[5], p0[6], p0[7]);
      ota[0] = mfma3216(VREAD(0, 0), f0, ota[0]);
      ota[1] = mfma3216(VREAD(1, 0), f0, ota[1]);
      const bf16x8 f1 = pfrag8(hi, p0[8], p0[9], p0[10], p0[11], p0[12], p0[13], p0[14], p0[15]);
      otb[0] = mfma3216(VREAD(0, 2), f1, otb[0]);
      otb[1] = mfma3216(VREAD(1, 2), f1, otb[1]);
    }
    // PV, keys kb*64 + 32..63
    {
      const bf16x8 f0 = pfrag8(hi, p1[0], p1[1], p1[2], p1[3], p1[4], p1[5], p1[6], p1[7]);
      ota[0] = mfma3216(VREAD(0, 4), f0, ota[0]);
      ota[1] = mfma3216(VREAD(1, 4), f0, ota[1]);
      const bf16x8 f1 = pfrag8(hi, p1[8], p1[9], p1[10], p1[11], p1[12], p1[13], p1[14], p1[15]);
      otb[0] = mfma3216(VREAD(0, 6), f1, otb[0]);
      otb[1] = mfma3216(VREAD(1, 6), f1, otb[1]);
    }
  }
#undef VREAD

  // epilogue: merge split accumulators; l over full key range = lp + partner-half lp
#pragma unroll
  for (int i = 0; i < 16; ++i) { ota[0][i] += otb[0][i]; ota[1][i] += otb[1][i]; }
  const float l = lp + __shfl_xor(lp, 32);
  const float inv = 1.0f / l;
  const int q = q0w + c31;
#pragma unroll
  for (int db = 0; db < 2; ++db) {
#pragma unroll
    for (int rg = 0; rg < 4; ++rg) {
      bf16x4 o;
#pragma unroll
      for (int i = 0; i < 4; ++i) o[i] = (__bf16)(ota[db][rg * 4 + i] * inv);
      const int d0 = db * 32 + rg * 8 + hi * 4;
      *(bf16x4*)(AOb + ((size_t)(b * S_LEN + q)) * DMODEL + h * DHEAD + d0) = o;
    }
  }
}

// ---------------------------------------------------------------- launch
extern "C" void kernel_launch(void* const* d_in, const int* in_sizes, int n_in,
                              void* d_out, int out_size, void* d_ws, size_t ws_size,
                              hipStream_t stream) {
  const float* x    = (const float*)d_in[0];
  const float* Wqkv = (const float*)d_in[1];
  const float* bqkv = (const float*)d_in[2];
  const float* Wout = (const float*)d_in[3];
  const float* bout = (const float*)d_in[4];
  float* out = (float*)d_out;

  char* ws = (char*)d_ws;
  __bf16* xb    = (__bf16*)(ws + 0);                          //  8 MB (4096x1024)
  __bf16* Wqkvb = (__bf16*)(ws + (size_t)8  * 1024 * 1024);   //  6 MB (3072x1024)
  __bf16* Woutb = (__bf16*)(ws + (size_t)14 * 1024 * 1024);   //  2 MB (1024x1024)
  __bf16* Qb    = (__bf16*)(ws + (size_t)16 * 1024 * 1024);   //  8 MB [bh][s][d] (pre-scaled)
  __bf16* Kb    = (__bf16*)(ws + (size_t)24 * 1024 * 1024);   //  8 MB [bh][s][d]
  __bf16* Vtb   = (__bf16*)(ws + (size_t)32 * 1024 * 1024);   //  8 MB [bh][d][s]
  __bf16* AOb   = (__bf16*)(ws + (size_t)40 * 1024 * 1024);   //  8 MB [b][s][dm]

  cvt_kernel<<<(TOK * DMODEL) / 1024, 256, 0, stream>>>(x, xb, TOK * DMODEL);
  cvt_kernel<<<(NQKV * DMODEL) / 1024, 256, 0, stream>>>(Wqkv, Wqkvb, NQKV * DMODEL);
  cvt_kernel<<<(DMODEL * DMODEL) / 1024, 256, 0, stream>>>(Wout, Woutb, DMODEL * DMODEL);

  gemm_qkv_kernel<<<dim3(NQKV / 128, TOK / 128), 256, 0, stream>>>(xb, Wqkvb, bqkv, Qb, Kb, Vtb);

  rope_kernel<<<(2 * BH_TOT * S_LEN * 16) / 256, 256, 0, stream>>>(Qb, Kb);

  attn_kernel<<<dim3(S_LEN / 128, BH_TOT), 256, 0, stream>>>(Qb, Kb, Vtb, AOb);

  gemm_out_kernel<<<dim3(DMODEL / 128, TOK / 128), 256, 0, stream>>>(AOb, Woutb, bout, out);
}

// Round 4
// 200.082 us; speedup vs baseline: 1.0220x; 1.0220x over previous
//
#include <hip/hip_runtime.h>

#define S_LEN 2048
#define DMODEL 1024
#define NHEAD 16
#define DHEAD 64
#define BATCH 2
#define BH_TOT (BATCH * NHEAD)   // 32
#define TOK (BATCH * S_LEN)      // 4096
#define NQKV (3 * DMODEL)        // 3072

// softmax scale 1/sqrt(64) = 0.125, fused with log2(e) so scores are in log2 domain
#define QSCALE 0.18033688011112042f

typedef float  f32x4  __attribute__((ext_vector_type(4)));
typedef float  f32x16 __attribute__((ext_vector_type(16)));
typedef int    i32x4  __attribute__((ext_vector_type(4)));
typedef unsigned u32x2 __attribute__((ext_vector_type(2)));
typedef __bf16 bf16x8 __attribute__((ext_vector_type(8)));
typedef __bf16 bf16x4 __attribute__((ext_vector_type(4)));
typedef __bf16 bf16x2 __attribute__((ext_vector_type(2)));

typedef __attribute__((address_space(1))) void* as1_ptr;
typedef __attribute__((address_space(3))) void* as3_ptr;

__device__ __forceinline__ void gl2lds16(const void* g, void* l) {
  __builtin_amdgcn_global_load_lds((as1_ptr)(void*)g, (as3_ptr)l, 16, 0, 0);
}

__device__ __forceinline__ f32x4 mfma32(bf16x8 a, bf16x8 b, f32x4 c) {
  return __builtin_amdgcn_mfma_f32_16x16x32_bf16(a, b, c, 0, 0, 0);
}

// 32x32x16 bf16: A[m=lane&31][k=(lane>>5)*8+j], B[k=(lane>>5)*8+j][n=lane&31]
// C/D: col=lane&31, row=(reg&3)+8*(reg>>2)+4*(lane>>5)
__device__ __forceinline__ f32x16 mfma3216(bf16x8 a, bf16x8 b, f32x16 c) {
  return __builtin_amdgcn_mfma_f32_32x32x16_bf16(a, b, c, 0, 0, 0);
}

// pack 2 f32 -> 1 word of 2 bf16 via scalar casts (compiler emits the pack)
__device__ __forceinline__ unsigned pack2(float a, float b) {
  bf16x2 t;
  t[0] = (__bf16)a;
  t[1] = (__bf16)b;
  return __builtin_bit_cast(unsigned, t);
}

// P B-fragment in the PERMUTED k-slot order (zero cross-lane ops).
// Slot (hi,j) <-> key 4*hi + (j<4 ? j : 4+j). P's natural post-QK^T register order
// p[r]=P[key=(r&3)+8*(r>>2)+4*hi] for r=0..7 is exactly this order packed pairwise.
__device__ __forceinline__ bf16x8 pfragn(float a0, float a1, float a2, float a3,
                                         float a4, float a5, float a6, float a7) {
  const i32x4 w = {(int)pack2(a0, a1), (int)pack2(a2, a3),
                   (int)pack2(a4, a5), (int)pack2(a6, a7)};
  return __builtin_bit_cast(bf16x8, w);
}

// ---------------------------------------------------------------- convert f32 -> bf16
__global__ __launch_bounds__(256) void cvt_kernel(const float* __restrict__ src,
                                                  __bf16* __restrict__ dst, int n) {
  const int i = (blockIdx.x * 256 + threadIdx.x) * 4;
  if (i >= n) return;
  const f32x4 v = *(const f32x4*)(src + i);
  bf16x4 o;
  o[0] = (__bf16)v[0]; o[1] = (__bf16)v[1]; o[2] = (__bf16)v[2]; o[3] = (__bf16)v[3];
  *(bf16x4*)(dst + i) = o;
}

// ---------------------------------------------------------------- 128x128 bf16 GEMM mainloop
__device__ __forceinline__ void gemm_tile_128(const __bf16* __restrict__ A,
                                              const __bf16* __restrict__ Bw,
                                              const int Kd, const int tileM, const int tileN,
                                              __bf16* As, __bf16* Bs, f32x4 acc[4][4]) {
  const int t    = threadIdx.x;
  const int lane = t & 63;
  const int wave = t >> 6;
  const int quad = lane >> 4;
  const int c    = lane & 15;
  const int wm   = (wave >> 1) << 6;
  const int wn   = (wave & 1) << 6;

  const int u0 = t, u1 = t + 256;
  const __bf16* gA0 = A  + (size_t)(tileM + (u0 >> 2)) * Kd + (u0 & 3) * 8;
  const __bf16* gA1 = A  + (size_t)(tileM + (u1 >> 2)) * Kd + (u1 & 3) * 8;
  const __bf16* gB0 = Bw + (size_t)(tileN + (u0 >> 2)) * Kd + (u0 & 3) * 8;
  const __bf16* gB1 = Bw + (size_t)(tileN + (u1 >> 2)) * Kd + (u1 & 3) * 8;
  __bf16* lA0 = As + u0 * 8; __bf16* lA1 = As + u1 * 8;
  __bf16* lB0 = Bs + u0 * 8; __bf16* lB1 = Bs + u1 * 8;

  for (int k0 = 0; k0 < Kd; k0 += 32) {
    gl2lds16(gA0 + k0, lA0);
    gl2lds16(gA1 + k0, lA1);
    gl2lds16(gB0 + k0, lB0);
    gl2lds16(gB1 + k0, lB1);
    __syncthreads();
    bf16x8 af[4], bfr[4];
#pragma unroll
    for (int mt = 0; mt < 4; ++mt)
      af[mt] = *(const bf16x8*)(As + (wm + mt * 16 + c) * 32 + quad * 8);
#pragma unroll
    for (int nt = 0; nt < 4; ++nt)
      bfr[nt] = *(const bf16x8*)(Bs + (wn + nt * 16 + c) * 32 + quad * 8);
#pragma unroll
    for (int mt = 0; mt < 4; ++mt)
#pragma unroll
      for (int nt = 0; nt < 4; ++nt)
        acc[mt][nt] = mfma32(af[mt], bfr[nt], acc[mt][nt]);
    __syncthreads();
  }
}

// ---------------------------------------------------------------- QKV projection (+V transpose fused, +Q log2-scale)
__global__ __launch_bounds__(256) void gemm_qkv_kernel(const __bf16* __restrict__ xb,
                                                       const __bf16* __restrict__ Wb,
                                                       const float* __restrict__ bias,
                                                       __bf16* __restrict__ Qb,
                                                       __bf16* __restrict__ Kb,
                                                       __bf16* __restrict__ Vtb) {
  __shared__ __align__(16) __bf16 As[128 * 32];
  __shared__ __align__(16) __bf16 Bs[128 * 32];
  f32x4 acc[4][4];
#pragma unroll
  for (int i = 0; i < 4; ++i)
#pragma unroll
    for (int j = 0; j < 4; ++j) acc[i][j] = (f32x4){0.f, 0.f, 0.f, 0.f};

  const int tileM = blockIdx.y * 128;
  const int tileN = blockIdx.x * 128;
  gemm_tile_128(xb, Wb, DMODEL, tileM, tileN, As, Bs, acc);

  const int t = threadIdx.x;
  const int lane = t & 63, wave = t >> 6;
  const int quad = lane >> 4, c = lane & 15;
  const int wm = (wave >> 1) << 6, wn = (wave & 1) << 6;

#pragma unroll
  for (int nt = 0; nt < 4; ++nt) {
    const int col = tileN + wn + nt * 16 + c;
    const float bv = bias[col];
    const int which = col >> 10;         // 0=q,1=k,2=v  (uniform within 16-col group)
    const int h  = (col >> 6) & 15;
    const int dh = col & 63;
    if (which == 2) {
#pragma unroll
      for (int mt = 0; mt < 4; ++mt) {
        const int row0 = tileM + wm + mt * 16 + quad * 4;
        const int bb = row0 >> 11;
        const int ss = row0 & (S_LEN - 1);
        bf16x4 o;
#pragma unroll
        for (int r = 0; r < 4; ++r) o[r] = (__bf16)(acc[mt][nt][r] + bv);
        *(bf16x4*)(Vtb + (((size_t)(bb * NHEAD + h)) * DHEAD + dh) * S_LEN + ss) = o;
      }
    } else {
      __bf16* dst = (which == 0) ? Qb : Kb;
      const float scl = (which == 0) ? QSCALE : 1.0f;
#pragma unroll
      for (int mt = 0; mt < 4; ++mt) {
#pragma unroll
        for (int r = 0; r < 4; ++r) {
          const int row = tileM + wm + mt * 16 + quad * 4 + r;
          const int bb = row >> 11;
          const int ss = row & (S_LEN - 1);
          dst[(((size_t)(bb * NHEAD + h)) * S_LEN + ss) * DHEAD + dh] =
              (__bf16)((acc[mt][nt][r] + bv) * scl);
        }
      }
    }
  }
}

// ---------------------------------------------------------------- output projection
__global__ __launch_bounds__(256) void gemm_out_kernel(const __bf16* __restrict__ AOb,
                                                       const __bf16* __restrict__ Wb,
                                                       const float* __restrict__ bout,
                                                       float* __restrict__ out) {
  __shared__ __align__(16) __bf16 As[128 * 32];
  __shared__ __align__(16) __bf16 Bs[128 * 32];
  f32x4 acc[4][4];
#pragma unroll
  for (int i = 0; i < 4; ++i)
#pragma unroll
    for (int j = 0; j < 4; ++j) acc[i][j] = (f32x4){0.f, 0.f, 0.f, 0.f};

  const int tileM = blockIdx.y * 128;
  const int tileN = blockIdx.x * 128;
  gemm_tile_128(AOb, Wb, DMODEL, tileM, tileN, As, Bs, acc);

  const int t = threadIdx.x;
  const int lane = t & 63, wave = t >> 6;
  const int quad = lane >> 4, c = lane & 15;
  const int wm = (wave >> 1) << 6, wn = (wave & 1) << 6;

#pragma unroll
  for (int nt = 0; nt < 4; ++nt) {
    const int col = tileN + wn + nt * 16 + c;
    const float bv = bout[col];
#pragma unroll
    for (int mt = 0; mt < 4; ++mt) {
#pragma unroll
      for (int r = 0; r < 4; ++r) {
        const int row = tileM + wm + mt * 16 + quad * 4 + r;
        out[(size_t)row * DMODEL + col] = acc[mt][nt][r] + bv;
      }
    }
  }
}

// ---------------------------------------------------------------- partial interleaved RoPE
__global__ __launch_bounds__(256) void rope_kernel(__bf16* __restrict__ Qb, __bf16* __restrict__ Kb) {
  const int idx = blockIdx.x * 256 + threadIdx.x;
  const int j  = idx & 15;
  const int s  = (idx >> 4) & (S_LEN - 1);
  const int bh = (idx >> 15) & (BH_TOT - 1);
  __bf16* base = (idx >> 20) ? Kb : Qb;
  bf16x2* p = (bf16x2*)(base + ((size_t)bh * S_LEN + s) * DHEAD) + j;
  bf16x2 v = *p;
  const float x1 = (float)v[0];
  const float x2 = (float)v[1];
  const float LOG2_10000 = 13.287712379549449f;
  const float inv = exp2f(-(float)j * (LOG2_10000 / 16.0f));
  const float ang = (float)s * inv;
  float sn, cs;
  sincosf(ang, &sn, &cs);
  bf16x2 o;
  o[0] = (__bf16)(x1 * cs - x2 * sn);
  o[1] = (__bf16)(x2 * cs + x1 * sn);
  *p = o;
}

// ---------------------------------------------------------------- flash attention R6
// block = 2 waves x 32 q = 64 q; grid (32, 32) = 1024 blocks -> 4 independent blocks/CU
// (4 barrier domains + 4 DMA streams; was 2 with 4-wave blocks). K/V^T double-buffered
// in LDS via global_load_lds, XOR-swizzled 16B chunks (chunk ^= row&7).
// Per 64-key tile, per wave:
//   S^T = K·Q^T : 8x mfma_f32_32x32x16_bf16 (K A-frags: 8x ds_read_b128 swizzled)
//   p = exp2(z) (no-max)
//   ZERO-SHUFFLE PV: B slot (hi,j) <-> key 4hi+(j<4?j:4+j) == P's natural register
//   order (4x pack2, no cross-lane ops); V^T A-frags read with the SAME permutation
//   (2x ds_read_b64 per frag). Contraction correct: same key<->slot bijection on A and B.
//   O^T += V^T·P^T : 8x mfma_f32_32x32x16_bf16
// s_setprio(1) around MFMA clusters (T5). l: ONE shfl_xor(32) at the end.
__global__ __launch_bounds__(128, 2) void attn_kernel(const __bf16* __restrict__ Qb,
                                                      const __bf16* __restrict__ Kb,
                                                      const __bf16* __restrict__ Vtb,
                                                      __bf16* __restrict__ AOb) {
  __shared__ __align__(16) __bf16 Ks[2][64 * 64];   // [key][d], swizzled
  __shared__ __align__(16) __bf16 Vts[2][64 * 64];  // [d][key], swizzled

  const int qt = blockIdx.x;
  const int bh = blockIdx.y;
  const int b = bh >> 4, h = bh & 15;
  const int t = threadIdx.x, wave = t >> 6, lane = t & 63;
  const int c31 = lane & 31, hi = lane >> 5;
  const int cx = c31 & 7;
  const size_t head = (size_t)bh * S_LEN * DHEAD;
  const int q0w = qt * 64 + wave * 32;   // this wave's first q

  // Q B-frags (resident): qf[s] = Q^T[k=d=s*16+hi*8+j][n=q=q0w+c31]
  bf16x8 qf[4];
#pragma unroll
  for (int s = 0; s < 4; ++s)
    qf[s] = *(const bf16x8*)(Qb + head + (size_t)(q0w + c31) * DHEAD + s * 16 + hi * 8);

  f32x16 zzero;
#pragma unroll
  for (int i = 0; i < 16; ++i) zzero[i] = 0.f;

  // O^T accumulators: [dblock]; lane holds d = dblock*32+(r&3)+8*(r>>2)+4*hi, q = c31.
  f32x16 ota[2], otb[2];
  ota[0] = zzero; ota[1] = zzero; otb[0] = zzero; otb[1] = zzero;
  float lp = 0.f;

  // staging: 512 16B units per tile (K and V each); 128 threads x 4 units.
  // unit u -> row=u>>3, chunk=u&7; source chunk XOR row&7
  const __bf16* kg[4];
  const __bf16* vg[4];
  int loff[4];
#pragma unroll
  for (int i = 0; i < 4; ++i) {
    const int u = t + 128 * i;
    const int r = u >> 3, ch = (u & 7) ^ (r & 7);
    kg[i] = Kb + head + (size_t)r * DHEAD + ch * 8;
    vg[i] = Vtb + ((size_t)bh * DHEAD + r) * S_LEN + ch * 8;
    loff[i] = u * 8;
  }

  // stage kb=0 into buffer 0
#pragma unroll
  for (int i = 0; i < 4; ++i) {
    gl2lds16(kg[i], &Ks[0][loff[i]]);
    gl2lds16(vg[i], &Vts[0][loff[i]]);
  }

// V^T A-frag in the permuted k-slot order: element j = V^T[d=row][key base + 4hi + (j<4?j:4+j)]
// = two b64 reads at chunks cb, cb+1 (XOR-swizzled), byte offset hi*8.
#define VREAD64(db, cb)                                                                   \
  __builtin_bit_cast(bf16x8, (i32x4){                                                     \
      (int)__builtin_bit_cast(u32x2, *(const bf16x4*)(&Vts[cur][((db)*32 + c31) * 64 +    \
                                  (((cb) ^ cx) * 8) + hi * 4]))[0],                       \
      (int)__builtin_bit_cast(u32x2, *(const bf16x4*)(&Vts[cur][((db)*32 + c31) * 64 +    \
                                  (((cb) ^ cx) * 8) + hi * 4]))[1],                       \
      (int)__builtin_bit_cast(u32x2, *(const bf16x4*)(&Vts[cur][((db)*32 + c31) * 64 +    \
                                  ((((cb) + 1) ^ cx) * 8) + hi * 4]))[0],                 \
      (int)__builtin_bit_cast(u32x2, *(const bf16x4*)(&Vts[cur][((db)*32 + c31) * 64 +    \
                                  ((((cb) + 1) ^ cx) * 8) + hi * 4]))[1]})

  for (int kb = 0; kb < S_LEN / 64; ++kb) {
    __syncthreads();   // drains this wave's DMA (vmcnt) + syncs both waves
    const int cur = kb & 1;
    if (kb + 1 < S_LEN / 64) {
      const int nxt = cur ^ 1;
      const int k0n = (kb + 1) * 64;
#pragma unroll
      for (int i = 0; i < 4; ++i) {
        gl2lds16(kg[i] + (size_t)k0n * DHEAD, &Ks[nxt][loff[i]]);
        gl2lds16(vg[i] + k0n, &Vts[nxt][loff[i]]);
      }
    }

    // K A-frags: A[m=key=kb2*32+c31][k=d=s*16+hi*8+j], XOR-swizzled b128
    bf16x8 kA0[4], kA1[4];
#pragma unroll
    for (int s = 0; s < 4; ++s) {
      kA0[s] = *(const bf16x8*)(&Ks[cur][c31 * 64 + (((s * 2 + hi) ^ cx) * 8)]);
      kA1[s] = *(const bf16x8*)(&Ks[cur][(32 + c31) * 64 + (((s * 2 + hi) ^ cx) * 8)]);
    }

    // S^T for both 32-key halves (interleaved -> dependent-MFMA distance 2)
    f32x16 z0 = zzero, z1 = zzero;
    __builtin_amdgcn_s_setprio(1);
#pragma unroll
    for (int s = 0; s < 4; ++s) {
      z0 = mfma3216(kA0[s], qf[s], z0);
      z1 = mfma3216(kA1[s], qf[s], z1);
    }
    __builtin_amdgcn_s_setprio(0);

    float p0[16], p1[16];
#pragma unroll
    for (int r = 0; r < 16; ++r) p0[r] = __builtin_amdgcn_exp2f(z0[r]);
#pragma unroll
    for (int r = 0; r < 16; ++r) p1[r] = __builtin_amdgcn_exp2f(z1[r]);

    lp += (((p0[0] + p0[1]) + (p0[2] + p0[3])) + ((p0[4] + p0[5]) + (p0[6] + p0[7])))
        + (((p0[8] + p0[9]) + (p0[10] + p0[11])) + ((p0[12] + p0[13]) + (p0[14] + p0[15])));
    lp += (((p1[0] + p1[1]) + (p1[2] + p1[3])) + ((p1[4] + p1[5]) + (p1[6] + p1[7])))
        + (((p1[8] + p1[9]) + (p1[10] + p1[11])) + ((p1[12] + p1[13]) + (p1[14] + p1[15])));

    __builtin_amdgcn_s_setprio(1);
    // PV, keys kb*64 + 0..31 : 16-key chunks at cb=0 (keys 0-15) and cb=2 (keys 16-31)
    {
      const bf16x8 f0 = pfragn(p0[0], p0[1], p0[2], p0[3], p0[4], p0[5], p0[6], p0[7]);
      ota[0] = mfma3216(VREAD64(0, 0), f0, ota[0]);
      ota[1] = mfma3216(VREAD64(1, 0), f0, ota[1]);
      const bf16x8 f1 = pfragn(p0[8], p0[9], p0[10], p0[11], p0[12], p0[13], p0[14], p0[15]);
      otb[0] = mfma3216(VREAD64(0, 2), f1, otb[0]);
      otb[1] = mfma3216(VREAD64(1, 2), f1, otb[1]);
    }
    // PV, keys kb*64 + 32..63 : cb=4 (keys 32-47) and cb=6 (keys 48-63)
    {
      const bf16x8 f0 = pfragn(p1[0], p1[1], p1[2], p1[3], p1[4], p1[5], p1[6], p1[7]);
      ota[0] = mfma3216(VREAD64(0, 4), f0, ota[0]);
      ota[1] = mfma3216(VREAD64(1, 4), f0, ota[1]);
      const bf16x8 f1 = pfragn(p1[8], p1[9], p1[10], p1[11], p1[12], p1[13], p1[14], p1[15]);
      otb[0] = mfma3216(VREAD64(0, 6), f1, otb[0]);
      otb[1] = mfma3216(VREAD64(1, 6), f1, otb[1]);
    }
    __builtin_amdgcn_s_setprio(0);
  }
#undef VREAD64

  // epilogue: merge split accumulators; l over full key range = lp + partner-half lp
#pragma unroll
  for (int i = 0; i < 16; ++i) { ota[0][i] += otb[0][i]; ota[1][i] += otb[1][i]; }
  const float l = lp + __shfl_xor(lp, 32);
  const float inv = 1.0f / l;
  const int q = q0w + c31;
#pragma unroll
  for (int db = 0; db < 2; ++db) {
#pragma unroll
    for (int rg = 0; rg < 4; ++rg) {
      bf16x4 o;
#pragma unroll
      for (int i = 0; i < 4; ++i) o[i] = (__bf16)(ota[db][rg * 4 + i] * inv);
      const int d0 = db * 32 + rg * 8 + hi * 4;
      *(bf16x4*)(AOb + ((size_t)(b * S_LEN + q)) * DMODEL + h * DHEAD + d0) = o;
    }
  }
}

// ---------------------------------------------------------------- launch
extern "C" void kernel_launch(void* const* d_in, const int* in_sizes, int n_in,
                              void* d_out, int out_size, void* d_ws, size_t ws_size,
                              hipStream_t stream) {
  const float* x    = (const float*)d_in[0];
  const float* Wqkv = (const float*)d_in[1];
  const float* bqkv = (const float*)d_in[2];
  const float* Wout = (const float*)d_in[3];
  const float* bout = (const float*)d_in[4];
  float* out = (float*)d_out;

  char* ws = (char*)d_ws;
  __bf16* xb    = (__bf16*)(ws + 0);                          //  8 MB (4096x1024)
  __bf16* Wqkvb = (__bf16*)(ws + (size_t)8  * 1024 * 1024);   //  6 MB (3072x1024)
  __bf16* Woutb = (__bf16*)(ws + (size_t)14 * 1024 * 1024);   //  2 MB (1024x1024)
  __bf16* Qb    = (__bf16*)(ws + (size_t)16 * 1024 * 1024);   //  8 MB [bh][s][d] (pre-scaled)
  __bf16* Kb    = (__bf16*)(ws + (size_t)24 * 1024 * 1024);   //  8 MB [bh][s][d]
  __bf16* Vtb   = (__bf16*)(ws + (size_t)32 * 1024 * 1024);   //  8 MB [bh][d][s]
  __bf16* AOb   = (__bf16*)(ws + (size_t)40 * 1024 * 1024);   //  8 MB [b][s][dm]

  cvt_kernel<<<(TOK * DMODEL) / 1024, 256, 0, stream>>>(x, xb, TOK * DMODEL);
  cvt_kernel<<<(NQKV * DMODEL) / 1024, 256, 0, stream>>>(Wqkv, Wqkvb, NQKV * DMODEL);
  cvt_kernel<<<(DMODEL * DMODEL) / 1024, 256, 0, stream>>>(Wout, Woutb, DMODEL * DMODEL);

  gemm_qkv_kernel<<<dim3(NQKV / 128, TOK / 128), 256, 0, stream>>>(xb, Wqkvb, bqkv, Qb, Kb, Vtb);

  rope_kernel<<<(2 * BH_TOT * S_LEN * 16) / 256, 256, 0, stream>>>(Qb, Kb);

  attn_kernel<<<dim3(S_LEN / 64, BH_TOT), 128, 0, stream>>>(Qb, Kb, Vtb, AOb);

  gemm_out_kernel<<<dim3(DMODEL / 128, TOK / 128), 256, 0, stream>>>(AOb, Woutb, bout, out);
}